// Round 6
// baseline (651.759 us; speedup 1.0000x reference)
//
#include <hip/hip_runtime.h>
#include <math.h>

#define B_   16
#define L_   8192
#define D_   64
#define R_   4
#define NB_  128   // n_buckets = L/64
#define NH_  64    // rand_matrix last dim = n_buckets/2

typedef float v2f __attribute__((ext_vector_type(2)));

// DPP helpers: quad-local (4-lane) broadcast / butterfly — pure VALU, no LDS pipe.
__device__ __forceinline__ float dpp_xor1(float x) {
    return __int_as_float(__builtin_amdgcn_mov_dpp(__float_as_int(x), 0xB1, 0xf, 0xf, true)); // quad_perm(1,0,3,2)
}
__device__ __forceinline__ float dpp_xor2(float x) {
    return __int_as_float(__builtin_amdgcn_mov_dpp(__float_as_int(x), 0x4E, 0xf, 0xf, true)); // quad_perm(2,3,0,1)
}
__device__ __forceinline__ float quad_bcast0(float x) {
    return __int_as_float(__builtin_amdgcn_mov_dpp(__float_as_int(x), 0x00, 0xf, 0xf, true));
}
__device__ __forceinline__ float quad_bcast1(float x) {
    return __int_as_float(__builtin_amdgcn_mov_dpp(__float_as_int(x), 0x55, 0xf, 0xf, true));
}
__device__ __forceinline__ float quad_bcast2(float x) {
    return __int_as_float(__builtin_amdgcn_mov_dpp(__float_as_int(x), 0xAA, 0xf, 0xf, true));
}
__device__ __forceinline__ float quad_bcast3(float x) {
    return __int_as_float(__builtin_amdgcn_mov_dpp(__float_as_int(x), 0xFF, 0xf, 0xf, true));
}

// ---------------- K1: normalize rand_matrix columns over d (fp64), store [b][r][n][d]
__global__ __launch_bounds__(64) void k_rmnorm(const float* __restrict__ rm, double* __restrict__ rmn) {
    int b = blockIdx.x >> 2, r = blockIdx.x & 3;
    int n = threadIdx.x;
    float v[D_];
    double ss = 0.0;
    #pragma unroll
    for (int d = 0; d < D_; ++d) {
        float f = rm[((size_t)(b * D_ + d) * R_ + r) * NH_ + n];
        v[d] = f;
        ss += (double)f * (double)f;
    }
    double nrm = sqrt(ss); if (nrm < 1e-12) nrm = 1e-12;
    double inv = 1.0 / nrm;
    double* o = rmn + ((size_t)(b * R_ + r) * NH_ + n) * D_;
    #pragma unroll
    for (int d = 0; d < D_; ++d) o[d] = (double)v[d] * inv;
}

// ---------------- K2: LSH hash — fp32 argmax with top-2 margin test, fp64 re-check for
// near-tie lanes. fp32 dot error bound ~1.4e-6*||q||; margin 1.2e-5*||q|| = 8x safety.
__global__ __launch_bounds__(256) void k_hash(const float* __restrict__ q, const double* __restrict__ rmn,
                                              float* __restrict__ rn, int* __restrict__ h) {
    __shared__ double rmd[NH_ * D_]; // 32 KB
    __shared__ float  rms[NH_ * D_]; // 16 KB
    int b = blockIdx.z, r = blockIdx.y;
    int l = blockIdx.x * 256 + threadIdx.x;
    const double* src = rmn + (size_t)(b * R_ + r) * NH_ * D_;
    for (int i = threadIdx.x; i < NH_ * D_; i += 256) {
        double dv = src[i];
        rmd[i] = dv;
        rms[i] = (float)dv;
    }
    const float* qp = q + ((size_t)b * L_ + l) * D_;
    float qf[D_];
    double ss = 0.0;
    #pragma unroll
    for (int d = 0; d < D_; d += 4) {
        float4 f = *(const float4*)(qp + d);
        qf[d] = f.x; qf[d+1] = f.y; qf[d+2] = f.z; qf[d+3] = f.w;
        ss += (double)f.x * f.x + (double)f.y * f.y + (double)f.z * f.z + (double)f.w * f.w;
    }
    __syncthreads();
    float best = -1.0e30f, second = -1.0e30f; int bi = 0;
    for (int n = 0; n < NH_; ++n) {
        const float* kp = &rms[n * D_];
        float a0 = 0, a1 = 0, a2 = 0, a3 = 0;
        #pragma unroll
        for (int d = 0; d < D_; d += 4) {
            a0 = fmaf(qf[d],   kp[d],   a0);
            a1 = fmaf(qf[d+1], kp[d+1], a1);
            a2 = fmaf(qf[d+2], kp[d+2], a2);
            a3 = fmaf(qf[d+3], kp[d+3], a3);
        }
        float s = (a0 + a1) + (a2 + a3);
        if (s > best)       { second = best; best = s; bi = n; }
        else if (s > second)  second = s;
        float ns = -s;
        if (ns > best)      { second = best; best = ns; bi = n + NH_; }
        else if (ns > second) second = ns;
    }
    float qn = (float)sqrt(ss);
    if (best - second < 1.2e-5f * qn + 1.0e-7f) {
        // near-tie: redo exactly as the proven fp64 path
        double qd[D_];
        #pragma unroll
        for (int d = 0; d < D_; ++d) qd[d] = (double)qf[d];
        double bestd = -1.0e300; bi = 0;
        for (int n = 0; n < NH_; ++n) {
            const double* kp = &rmd[n * D_];
            double a0 = 0, a1 = 0, a2 = 0, a3 = 0;
            #pragma unroll
            for (int d = 0; d < D_; d += 4) {
                a0 = fma(qd[d],   kp[d],   a0);
                a1 = fma(qd[d+1], kp[d+1], a1);
                a2 = fma(qd[d+2], kp[d+2], a2);
                a3 = fma(qd[d+3], kp[d+3], a3);
            }
            double s = (a0 + a1) + (a2 + a3);
            if (s > bestd)  { bestd = s;  bi = n; }
            if (-s > bestd) { bestd = -s; bi = n + NH_; }
        }
    }
    h[(size_t)(b * R_ + r) * L_ + l] = bi;
    if (r == 0) {
        double nrm = sqrt(ss); if (nrm < 1e-12) nrm = 1e-12;
        rn[(size_t)b * L_ + l] = (float)(1.0 / nrm);
    }
}

// ---------------- K3: stable counting sort by bucket per (b,r); 1 wave per block
__global__ __launch_bounds__(64) void k_sort(const int* __restrict__ h, int* __restrict__ idx,
                                             int* __restrict__ sb, int* __restrict__ iv) {
    __shared__ unsigned int cnt[NB_ * 64]; // [bucket][thread], 32 KB
    int br = blockIdx.x;
    const int* hh = h + (size_t)br * L_;
    int t = threadIdx.x;
    for (int i = t; i < NB_ * 64; i += 64) cnt[i] = 0;
    __syncthreads();
    int base = t * 128;                      // each thread owns 128 consecutive l
    for (int i = 0; i < 128; ++i) { int bk = hh[base + i]; cnt[bk * 64 + t]++; }
    __syncthreads();
    int fb = t * 128;
    unsigned int local = 0;
    for (int i = 0; i < 128; ++i) local += cnt[fb + i];
    unsigned int v = local;
    #pragma unroll
    for (int off = 1; off < 64; off <<= 1) {
        unsigned int u = __shfl_up(v, off);
        if (t >= off) v += u;
    }
    unsigned int run = v - local; // exclusive base for this thread's 128 cells
    for (int i = 0; i < 128; ++i) { unsigned int c0 = cnt[fb + i]; cnt[fb + i] = run; run += c0; }
    __syncthreads();
    int* oi = idx + (size_t)br * L_;
    int* ob = sb  + (size_t)br * L_;
    int* ivp = iv + (size_t)br * L_;
    for (int i = 0; i < 128; ++i) {
        int l = base + i; int bk = hh[l];
        unsigned int pos = cnt[bk * 64 + t]++;
        oi[pos] = l; ob[pos] = bk; ivp[l] = (int)pos;
    }
}

// ---------------- K4: fused flash pass — QK^T, static-max softmax, PV in one sweep.
// Block = 256 threads = 4 INDEPENDENT waves, each handling one chunk (c = bx*4 + wave)
// in its own LDS slice. No __syncthreads anywhere: within a wave, LDS write->read
// ordering is enforced by the compiler's lgkmcnt waits. This gives 4-wave workgroups
// (the per-CU workgroup-slot cap was limiting 1-wave blocks to ~7 waves/CU).
// Quad layout per wave: lanes (4t..4t+3) own queries 4t..4t+3; lane h holds dims
// h*16..h*16+15 of all 4 queries. LDS rows stored as 4 slices at stride 20 words
// (conflict-free broadcast b128). QK/PV use 2-wide packed fp32 FMA (v_pk_fma_f32).
// Static max: scores for query i bounded by ||q_i||/8 = 0.125/rn — no online rescaling.
// omode: 0 = store O/sum + lse, contrib indexed [(b*R+r)*L + pos] (tierA)
//        1 = same but contrib indexed [b*L + pos] (tierB per-round slice)
//        2 = lse only (tierC pass 1)
//        3 = atomic w-weighted add into out (tierC pass 2; needs gm/gs)
__global__ __launch_bounds__(256, 3) void k_flash(const float* __restrict__ q, const float* __restrict__ val,
                                                  const int* __restrict__ idx, const int* __restrict__ sb,
                                                  const float* __restrict__ rn, float* __restrict__ lse,
                                                  const float* __restrict__ gm, const float* __restrict__ gs,
                                                  float* __restrict__ out, float* __restrict__ contrib,
                                                  int r_fixed, int omode) {
    __shared__ float kt[4][16 * 80];   // per-wave: 16 rows x 4 slices @ stride 20 words
    __shared__ float vt[4][16 * 80];
    __shared__ int   kqs[4][16];
    __shared__ int   kbs[4][16];
    __shared__ float krs[4][16];
    int w   = threadIdx.x >> 6;
    int tid = threadIdx.x & 63;
    int c = blockIdx.x * 4 + w, b = blockIdx.z;
    int r = (r_fixed < 0) ? (int)blockIdx.y : r_fixed;
    size_t sbase = (size_t)(b * R_ + r) * L_;
    int h = tid & 3;
    int posq = c * 64 + (tid >> 2) * 4;           // first query of this lane's quad
    int mls[4];
    #pragma unroll
    for (int qq = 0; qq < 4; ++qq) mls[qq] = idx[sbase + posq + qq];
    int ownpos  = posq + h;
    int myl_own = idx[sbase + ownpos];
    int mybk_own = sb[sbase + ownpos];
    float m_own = 0.125f / rn[(size_t)b * L_ + myl_own];   // = ||q_own||/8
    const float* qb = q   + (size_t)b * L_ * D_;
    const float* vb = val + (size_t)b * L_ * D_;
    v2f qv2[4][8];
    #pragma unroll
    for (int qq = 0; qq < 4; ++qq) {
        const float* qp = qb + (size_t)mls[qq] * D_ + h * 16;
        #pragma unroll
        for (int i = 0; i < 16; i += 4) {
            float4 f = *(const float4*)(qp + i);
            qv2[qq][i >> 1]       = (v2f){f.x, f.y};
            qv2[qq][(i >> 1) + 1] = (v2f){f.z, f.w};
        }
    }
    float ps[4] = {0.0f, 0.0f, 0.0f, 0.0f};
    v2f acc2[4][8];
    #pragma unroll
    for (int qq = 0; qq < 4; ++qq)
        #pragma unroll
        for (int i = 0; i < 8; ++i) acc2[qq][i] = (v2f){0.0f, 0.0f};

    #pragma unroll 1
    for (int s = 0; s < 8; ++s) {   // 8 stages of 16 keys: prev chunk (4) then current (4)
        int ck = ((c + NB_ - 1 + (s >> 2)) & (NB_ - 1)) * 64 + (s & 3) * 16;
        {
            int rw = tid >> 2, cc = tid & 3;
            int kl = idx[sbase + ck + rw];
            const float* kp = qb + (size_t)kl * D_ + cc * 16;
            float* kd = &kt[w][rw * 80 + cc * 20];
            #pragma unroll
            for (int i = 0; i < 16; i += 4) *(float4*)(kd + i) = *(const float4*)(kp + i);
            if (omode != 2) {
                const float* vp = vb + (size_t)kl * D_ + cc * 16;
                float* vd = &vt[w][rw * 80 + cc * 20];
                #pragma unroll
                for (int i = 0; i < 16; i += 4) *(float4*)(vd + i) = *(const float4*)(vp + i);
            }
            if (tid < 16) {
                int kl2 = idx[sbase + ck + tid];
                kqs[w][tid] = kl2;
                kbs[w][tid] = sb[sbase + ck + tid];
                krs[w][tid] = rn[(size_t)b * L_ + kl2] * 0.125f;
            }
        }
        // no barrier: single-wave producer/consumer, lgkmcnt ordering suffices
        #pragma unroll
        for (int j = 0; j < 16; ++j) {
            const float* kpj = &kt[w][j * 80 + h * 20];
            v2f a0 = (v2f){0.f, 0.f}, a1 = a0, a2 = a0, a3 = a0;
            #pragma unroll
            for (int i = 0; i < 16; i += 4) {
                float4 kk = *(const float4*)(kpj + i);
                v2f kA = (v2f){kk.x, kk.y}, kB = (v2f){kk.z, kk.w};
                int i2 = i >> 1;
                a0 = __builtin_elementwise_fma(qv2[0][i2], kA, a0);
                a0 = __builtin_elementwise_fma(qv2[0][i2 + 1], kB, a0);
                a1 = __builtin_elementwise_fma(qv2[1][i2], kA, a1);
                a1 = __builtin_elementwise_fma(qv2[1][i2 + 1], kB, a1);
                a2 = __builtin_elementwise_fma(qv2[2][i2], kA, a2);
                a2 = __builtin_elementwise_fma(qv2[2][i2 + 1], kB, a2);
                a3 = __builtin_elementwise_fma(qv2[3][i2], kA, a3);
                a3 = __builtin_elementwise_fma(qv2[3][i2 + 1], kB, a3);
            }
            float p0 = a0.x + a0.y, p1 = a1.x + a1.y, p2 = a2.x + a2.y, p3 = a3.x + a3.y;
            // 4x4 transpose-reduce across the quad: lane h ends with query h's full dot
            bool b0 = (h & 1), b1 = (h & 2) != 0;
            float u0 = b0 ? p1 : p0;
            float t0 = b0 ? p0 : p1;
            u0 += dpp_xor1(t0);
            float u2 = b0 ? p3 : p2;
            float t2 = b0 ? p2 : p3;
            u2 += dpp_xor1(t2);
            float dot = b1 ? u2 : u0;
            float t3 = b1 ? u0 : u2;
            dot += dpp_xor2(t3);
            float sc = dot * krs[w][j];
            sc = (kbs[w][j] == mybk_own) ? sc : -1.0e9f;   // cross-bucket mask
            if (kqs[w][j] == myl_own) sc = -1.0e5f;         // self mask (overrides, as in ref)
            float p = __expf(sc - m_own);                   // static max: no rescaling ever
            ps[j & 3] += p;
            if (omode != 2) {
                v2f P0 = (v2f){quad_bcast0(p), quad_bcast0(p)};
                v2f P1 = (v2f){quad_bcast1(p), quad_bcast1(p)};
                v2f P2 = (v2f){quad_bcast2(p), quad_bcast2(p)};
                v2f P3 = (v2f){quad_bcast3(p), quad_bcast3(p)};
                const float* vpj = &vt[w][j * 80 + h * 20];
                #pragma unroll
                for (int i = 0; i < 16; i += 4) {
                    float4 vv = *(const float4*)(vpj + i);
                    v2f vA = (v2f){vv.x, vv.y}, vB = (v2f){vv.z, vv.w};
                    int i2 = i >> 1;
                    acc2[0][i2]     = __builtin_elementwise_fma(P0, vA, acc2[0][i2]);
                    acc2[0][i2 + 1] = __builtin_elementwise_fma(P0, vB, acc2[0][i2 + 1]);
                    acc2[1][i2]     = __builtin_elementwise_fma(P1, vA, acc2[1][i2]);
                    acc2[1][i2 + 1] = __builtin_elementwise_fma(P1, vB, acc2[1][i2 + 1]);
                    acc2[2][i2]     = __builtin_elementwise_fma(P2, vA, acc2[2][i2]);
                    acc2[2][i2 + 1] = __builtin_elementwise_fma(P2, vB, acc2[2][i2 + 1]);
                    acc2[3][i2]     = __builtin_elementwise_fma(P3, vA, acc2[3][i2]);
                    acc2[3][i2 + 1] = __builtin_elementwise_fma(P3, vB, acc2[3][i2 + 1]);
                }
            }
        }
    }
    float sum = (ps[0] + ps[1]) + (ps[2] + ps[3]);
    float lse_own, inv_own;
    if (sum > 0.0f) { lse_own = m_own + logf(sum); inv_own = 1.0f / sum; }
    else            { lse_own = -3.0e38f;          inv_own = 0.0f; }   // fully-masked row
    if (omode != 3) lse[sbase + ownpos] = lse_own;
    if (omode == 0 || omode == 1) {
        float ivs[4];
        ivs[0] = quad_bcast0(inv_own); ivs[1] = quad_bcast1(inv_own);
        ivs[2] = quad_bcast2(inv_own); ivs[3] = quad_bcast3(inv_own);
        float* cbase = contrib + ((omode == 0) ? (size_t)(b * R_ + r) * L_ : (size_t)b * L_) * D_;
        #pragma unroll
        for (int qq = 0; qq < 4; ++qq) {
            float* cp = cbase + (size_t)(posq + qq) * D_ + h * 16;
            #pragma unroll
            for (int i = 0; i < 16; i += 4) {
                int i2 = i >> 1;
                float4 o;
                o.x = acc2[qq][i2].x * ivs[qq];     o.y = acc2[qq][i2].y * ivs[qq];
                o.z = acc2[qq][i2 + 1].x * ivs[qq]; o.w = acc2[qq][i2 + 1].y * ivs[qq];
                *(float4*)(cp + i) = o;
            }
        }
    } else if (omode == 3) {
        int brr = b * R_ + r;
        float gmv = gm[brr], gsv = gs[brr];
        float ls4[4], iv4[4];
        ls4[0] = quad_bcast0(lse_own); ls4[1] = quad_bcast1(lse_own);
        ls4[2] = quad_bcast2(lse_own); ls4[3] = quad_bcast3(lse_own);
        iv4[0] = quad_bcast0(inv_own); iv4[1] = quad_bcast1(inv_own);
        iv4[2] = quad_bcast2(inv_own); iv4[3] = quad_bcast3(inv_own);
        #pragma unroll
        for (int qq = 0; qq < 4; ++qq) {
            float wq = __expf(ls4[qq] - gmv) * gsv * iv4[qq];
            float* op = out + ((size_t)b * L_ + mls[qq]) * D_ + h * 16;
            #pragma unroll
            for (int i = 0; i < 8; ++i) {
                unsafeAtomicAdd(op + 2 * i,     wq * acc2[qq][i].x);
                unsafeAtomicAdd(op + 2 * i + 1, wq * acc2[qq][i].y);
            }
        }
    }
}

// ---------------- K5: softmax-over-L normalizers (max + fp64 sum) per (b,r)
__global__ __launch_bounds__(256) void k_wred(const float* __restrict__ lse, float* __restrict__ gm,
                                              float* __restrict__ gs, int r_w) {
    __shared__ float  sm[4];
    __shared__ double sd[4];
    int br = (r_w < 0) ? (int)blockIdx.x : ((int)blockIdx.x * R_ + r_w);
    const float* x = lse + (size_t)br * L_;
    int t = threadIdx.x;
    float mx = -3.0e38f;
    for (int i = t; i < L_; i += 256) mx = fmaxf(mx, x[i]);
    #pragma unroll
    for (int o = 32; o; o >>= 1) mx = fmaxf(mx, __shfl_down(mx, o));
    if ((t & 63) == 0) sm[t >> 6] = mx;
    __syncthreads();
    mx = fmaxf(fmaxf(sm[0], sm[1]), fmaxf(sm[2], sm[3]));
    double s = 0.0;
    for (int i = t; i < L_; i += 256) s += exp((double)x[i] - (double)mx);
    #pragma unroll
    for (int o = 32; o; o >>= 1) s += __shfl_down(s, o);
    if ((t & 63) == 0) sd[t >> 6] = s;
    __syncthreads();
    if (t == 0) { gm[br] = mx; gs[br] = (float)(1.0 / (sd[0] + sd[1] + sd[2] + sd[3])); }
}

// ---------------- K6a: gather all 4 rounds from full contrib, apply w, write out
__global__ __launch_bounds__(256) void k_comb_full(const float* __restrict__ contrib,
                                                   const int* __restrict__ iv,
                                                   const float* __restrict__ lse,
                                                   const float* __restrict__ gm,
                                                   const float* __restrict__ gs,
                                                   float* __restrict__ out) {
    int gid = blockIdx.x * 256 + threadIdx.x;
    int row = gid >> 2;              // b*L + l
    int ch  = (gid & 3) * 16;
    int b = row >> 13, l = row & (L_ - 1);
    float s[16];
    #pragma unroll
    for (int i = 0; i < 16; ++i) s[i] = 0.0f;
    #pragma unroll
    for (int r = 0; r < R_; ++r) {
        int brr = b * R_ + r;
        int pos = iv[(size_t)brr * L_ + l];
        float w = expf(lse[(size_t)brr * L_ + pos] - gm[brr]) * gs[brr];
        const float* cp = contrib + ((size_t)brr * L_ + pos) * D_ + ch;
        #pragma unroll
        for (int i = 0; i < 16; i += 4) {
            float4 f = *(const float4*)(cp + i);
            s[i]   = fmaf(w, f.x, s[i]);   s[i+1] = fmaf(w, f.y, s[i+1]);
            s[i+2] = fmaf(w, f.z, s[i+2]); s[i+3] = fmaf(w, f.w, s[i+3]);
        }
    }
    float* op = out + (size_t)row * D_ + ch;
    #pragma unroll
    for (int i = 0; i < 16; i += 4) {
        float4 o; o.x = s[i]; o.y = s[i+1]; o.z = s[i+2]; o.w = s[i+3];
        *(float4*)(op + i) = o;
    }
}

// ---------------- K6b: gather one round's slice, apply w, accumulate into out
__global__ __launch_bounds__(256) void k_comb_add(const float* __restrict__ contrib,
                                                  const int* __restrict__ iv,
                                                  const float* __restrict__ lse,
                                                  const float* __restrict__ gm,
                                                  const float* __restrict__ gs,
                                                  float* __restrict__ out, int r) {
    int gid = blockIdx.x * 256 + threadIdx.x;
    int row = gid >> 2;              // b*L + l
    int ch  = (gid & 3) * 16;
    int b = row >> 13, l = row & (L_ - 1);
    int brr = b * R_ + r;
    int pos = iv[(size_t)brr * L_ + l];
    float w = expf(lse[(size_t)brr * L_ + pos] - gm[brr]) * gs[brr];
    const float* cp = contrib + ((size_t)b * L_ + pos) * D_ + ch;
    float* op = out + (size_t)row * D_ + ch;
    #pragma unroll
    for (int i = 0; i < 16; i += 4) {
        float4 f = *(const float4*)(cp + i);
        float4 o = *(const float4*)(op + i);
        o.x = fmaf(w, f.x, o.x); o.y = fmaf(w, f.y, o.y);
        o.z = fmaf(w, f.z, o.z); o.w = fmaf(w, f.w, o.w);
        *(float4*)(op + i) = o;
    }
}

// ---------------- workspace layout (bytes)
#define OFF_RMN     0u
#define OFF_RN      2097152u
#define OFF_H       2621440u
#define OFF_IDX     4718592u
#define OFF_SB      6815744u
#define OFF_LSE     8912896u
#define OFF_GM      11010048u
#define OFF_GS      11010304u
#define OFF_INV     11010560u
#define OFF_CONTRIB 13107712u
#define CONTRIB_FULL_BYTES  134217728ull   // B*R*L*D*4 = 128 MiB
#define CONTRIB_SLICE_BYTES 33554432ull    // B*L*D*4   =  32 MiB

extern "C" void kernel_launch(void* const* d_in, const int* in_sizes, int n_in,
                              void* d_out, int out_size, void* d_ws, size_t ws_size,
                              hipStream_t stream) {
    const float* q  = (const float*)d_in[0];
    const float* v  = (const float*)d_in[1];
    const float* rm = (const float*)d_in[2];
    float* out = (float*)d_out;
    char* ws = (char*)d_ws;
    double* rmn = (double*)(ws + OFF_RMN);
    float*  rn  = (float*)(ws + OFF_RN);
    int*    h   = (int*)(ws + OFF_H);
    int*    idx = (int*)(ws + OFF_IDX);
    int*    sb  = (int*)(ws + OFF_SB);
    float*  lse = (float*)(ws + OFF_LSE);
    float*  gm  = (float*)(ws + OFF_GM);
    float*  gs  = (float*)(ws + OFF_GS);
    int*    iv  = (int*)(ws + OFF_INV);
    float*  contrib = (float*)(ws + OFF_CONTRIB);

    int tierA = (ws_size >= (size_t)OFF_CONTRIB + CONTRIB_FULL_BYTES) ? 1 : 0;
    int tierB = (!tierA && ws_size >= (size_t)OFF_CONTRIB + CONTRIB_SLICE_BYTES) ? 1 : 0;

    hipLaunchKernelGGL(k_rmnorm, dim3(B_ * R_), dim3(64), 0, stream, rm, rmn);
    hipLaunchKernelGGL(k_hash, dim3(L_ / 256, R_, B_), dim3(256), 0, stream, q, rmn, rn, h);
    hipLaunchKernelGGL(k_sort, dim3(B_ * R_), dim3(64), 0, stream, h, idx, sb, iv);

    if (tierA) {
        hipLaunchKernelGGL(k_flash, dim3(NB_ / 4, R_, B_), dim3(256), 0, stream, q, v, idx, sb, rn,
                           lse, gm, gs, out, contrib, -1, 0);
        hipLaunchKernelGGL(k_wred, dim3(B_ * R_), dim3(256), 0, stream, lse, gm, gs, -1);
        hipLaunchKernelGGL(k_comb_full, dim3(B_ * L_ * 4 / 256), dim3(256), 0, stream,
                           contrib, iv, lse, gm, gs, out);
    } else if (tierB) {
        hipMemsetAsync(d_out, 0, (size_t)B_ * L_ * D_ * sizeof(float), stream);
        for (int r = 0; r < R_; ++r) {
            hipLaunchKernelGGL(k_flash, dim3(NB_ / 4, 1, B_), dim3(256), 0, stream, q, v, idx, sb, rn,
                               lse, gm, gs, out, contrib, r, 1);
            hipLaunchKernelGGL(k_wred, dim3(B_), dim3(256), 0, stream, lse, gm, gs, r);
            hipLaunchKernelGGL(k_comb_add, dim3(B_ * L_ * 4 / 256), dim3(256), 0, stream,
                               contrib, iv, lse, gm, gs, out, r);
        }
    } else {
        // tier C: two flash passes (lse-only, then atomic w-weighted accumulate)
        hipMemsetAsync(d_out, 0, (size_t)B_ * L_ * D_ * sizeof(float), stream);
        hipLaunchKernelGGL(k_flash, dim3(NB_ / 4, R_, B_), dim3(256), 0, stream, q, v, idx, sb, rn,
                           lse, gm, gs, out, contrib, -1, 2);
        hipLaunchKernelGGL(k_wred, dim3(B_ * R_), dim3(256), 0, stream, lse, gm, gs, -1);
        hipLaunchKernelGGL(k_flash, dim3(NB_ / 4, R_, B_), dim3(256), 0, stream, q, v, idx, sb, rn,
                           lse, gm, gs, out, contrib, -1, 3);
    }
}

// Round 7
// 557.645 us; speedup vs baseline: 1.1688x; 1.1688x over previous
//
#include <hip/hip_runtime.h>
#include <math.h>

#define B_   16
#define L_   8192
#define D_   64
#define R_   4
#define NB_  128   // n_buckets = L/64
#define NH_  64    // rand_matrix last dim = n_buckets/2

typedef float v2f __attribute__((ext_vector_type(2)));

// DPP helpers: quad-local (4-lane) broadcast / butterfly — pure VALU, no LDS pipe.
__device__ __forceinline__ float dpp_xor1(float x) {
    return __int_as_float(__builtin_amdgcn_mov_dpp(__float_as_int(x), 0xB1, 0xf, 0xf, true)); // quad_perm(1,0,3,2)
}
__device__ __forceinline__ float dpp_xor2(float x) {
    return __int_as_float(__builtin_amdgcn_mov_dpp(__float_as_int(x), 0x4E, 0xf, 0xf, true)); // quad_perm(2,3,0,1)
}
__device__ __forceinline__ float quad_bcast0(float x) {
    return __int_as_float(__builtin_amdgcn_mov_dpp(__float_as_int(x), 0x00, 0xf, 0xf, true));
}
__device__ __forceinline__ float quad_bcast1(float x) {
    return __int_as_float(__builtin_amdgcn_mov_dpp(__float_as_int(x), 0x55, 0xf, 0xf, true));
}
__device__ __forceinline__ float quad_bcast2(float x) {
    return __int_as_float(__builtin_amdgcn_mov_dpp(__float_as_int(x), 0xAA, 0xf, 0xf, true));
}
__device__ __forceinline__ float quad_bcast3(float x) {
    return __int_as_float(__builtin_amdgcn_mov_dpp(__float_as_int(x), 0xFF, 0xf, 0xf, true));
}

// ---------------- K1: normalize rand_matrix columns over d (fp64), store [b][r][n][d]
__global__ __launch_bounds__(64) void k_rmnorm(const float* __restrict__ rm, double* __restrict__ rmn) {
    int b = blockIdx.x >> 2, r = blockIdx.x & 3;
    int n = threadIdx.x;
    float v[D_];
    double ss = 0.0;
    #pragma unroll
    for (int d = 0; d < D_; ++d) {
        float f = rm[((size_t)(b * D_ + d) * R_ + r) * NH_ + n];
        v[d] = f;
        ss += (double)f * (double)f;
    }
    double nrm = sqrt(ss); if (nrm < 1e-12) nrm = 1e-12;
    double inv = 1.0 / nrm;
    double* o = rmn + ((size_t)(b * R_ + r) * NH_ + n) * D_;
    #pragma unroll
    for (int d = 0; d < D_; ++d) o[d] = (double)v[d] * inv;
}

// ---------------- K2: LSH hash — packed-fp32 argmax with top-2 margin test, fp64 re-check
// for near-tie lanes. fp32 dot error bound ~1.4e-6*||q||; margin 1.2e-5*||q|| = 8x safety.
__global__ __launch_bounds__(256) void k_hash(const float* __restrict__ q, const double* __restrict__ rmn,
                                              float* __restrict__ rn, int* __restrict__ h) {
    __shared__ double rmd[NH_ * D_]; // 32 KB
    __shared__ float  rms[NH_ * D_]; // 16 KB
    int b = blockIdx.z, r = blockIdx.y;
    int l = blockIdx.x * 256 + threadIdx.x;
    const double* src = rmn + (size_t)(b * R_ + r) * NH_ * D_;
    for (int i = threadIdx.x; i < NH_ * D_; i += 256) {
        double dv = src[i];
        rmd[i] = dv;
        rms[i] = (float)dv;
    }
    const float* qp = q + ((size_t)b * L_ + l) * D_;
    v2f qv2[D_ / 2];
    double ss = 0.0;
    #pragma unroll
    for (int d = 0; d < D_; d += 4) {
        float4 f = *(const float4*)(qp + d);
        qv2[d >> 1]       = (v2f){f.x, f.y};
        qv2[(d >> 1) + 1] = (v2f){f.z, f.w};
        ss += (double)f.x * f.x + (double)f.y * f.y + (double)f.z * f.z + (double)f.w * f.w;
    }
    __syncthreads();
    float best = -1.0e30f, second = -1.0e30f; int bi = 0;
    for (int n = 0; n < NH_; ++n) {
        const float* kp = &rms[n * D_];
        v2f a0 = (v2f){0.f, 0.f}, a1 = a0;
        #pragma unroll
        for (int d = 0; d < D_; d += 4) {
            float4 kk = *(const float4*)(kp + d);
            a0 = __builtin_elementwise_fma(qv2[d >> 1],       (v2f){kk.x, kk.y}, a0);
            a1 = __builtin_elementwise_fma(qv2[(d >> 1) + 1], (v2f){kk.z, kk.w}, a1);
        }
        float s = (a0.x + a0.y) + (a1.x + a1.y);
        if (s > best)       { second = best; best = s; bi = n; }
        else if (s > second)  second = s;
        float ns = -s;
        if (ns > best)      { second = best; best = ns; bi = n + NH_; }
        else if (ns > second) second = ns;
    }
    float qn = (float)sqrt(ss);
    if (best - second < 1.2e-5f * qn + 1.0e-7f) {
        // near-tie: redo exactly as the proven fp64 path
        double qd[D_];
        #pragma unroll
        for (int d = 0; d < D_; d += 2) {
            qd[d] = (double)qv2[d >> 1].x; qd[d + 1] = (double)qv2[d >> 1].y;
        }
        double bestd = -1.0e300; bi = 0;
        for (int n = 0; n < NH_; ++n) {
            const double* kp = &rmd[n * D_];
            double a0 = 0, a1 = 0, a2 = 0, a3 = 0;
            #pragma unroll
            for (int d = 0; d < D_; d += 4) {
                a0 = fma(qd[d],   kp[d],   a0);
                a1 = fma(qd[d+1], kp[d+1], a1);
                a2 = fma(qd[d+2], kp[d+2], a2);
                a3 = fma(qd[d+3], kp[d+3], a3);
            }
            double s = (a0 + a1) + (a2 + a3);
            if (s > bestd)  { bestd = s;  bi = n; }
            if (-s > bestd) { bestd = -s; bi = n + NH_; }
        }
    }
    h[(size_t)(b * R_ + r) * L_ + l] = bi;
    if (r == 0) {
        double nrm = sqrt(ss); if (nrm < 1e-12) nrm = 1e-12;
        rn[(size_t)b * L_ + l] = (float)(1.0 / nrm);
    }
}

// ---------------- K3: stable counting sort by bucket per (b,r); 1 wave per block
__global__ __launch_bounds__(64) void k_sort(const int* __restrict__ h, int* __restrict__ idx,
                                             int* __restrict__ sb, int* __restrict__ iv) {
    __shared__ unsigned int cnt[NB_ * 64]; // [bucket][thread], 32 KB
    int br = blockIdx.x;
    const int* hh = h + (size_t)br * L_;
    int t = threadIdx.x;
    for (int i = t; i < NB_ * 64; i += 64) cnt[i] = 0;
    __syncthreads();
    int base = t * 128;                      // each thread owns 128 consecutive l
    for (int i = 0; i < 128; ++i) { int bk = hh[base + i]; cnt[bk * 64 + t]++; }
    __syncthreads();
    int fb = t * 128;
    unsigned int local = 0;
    for (int i = 0; i < 128; ++i) local += cnt[fb + i];
    unsigned int v = local;
    #pragma unroll
    for (int off = 1; off < 64; off <<= 1) {
        unsigned int u = __shfl_up(v, off);
        if (t >= off) v += u;
    }
    unsigned int run = v - local; // exclusive base for this thread's 128 cells
    for (int i = 0; i < 128; ++i) { unsigned int c0 = cnt[fb + i]; cnt[fb + i] = run; run += c0; }
    __syncthreads();
    int* oi = idx + (size_t)br * L_;
    int* ob = sb  + (size_t)br * L_;
    int* ivp = iv + (size_t)br * L_;
    for (int i = 0; i < 128; ++i) {
        int l = base + i; int bk = hh[l];
        unsigned int pos = cnt[bk * 64 + t]++;
        oi[pos] = l; ob[pos] = bk; ivp[l] = (int)pos;
    }
}

// ---------------- K4: fused flash pass — QK^T, static-max softmax, PV in one sweep.
// Block = 128 threads = 2 INDEPENDENT waves, each handling one chunk (c = bx*2 + wave)
// in its own LDS slice. No __syncthreads: within a wave, LDS write->read ordering is
// enforced by the compiler's lgkmcnt waits (validated in R6). 2-wave blocks pack better:
// LDS 21 KB/block -> up to 7 blocks/CU; VGPR unconstrained (no spill) -> ~3 waves/EU.
// Quad layout per wave: lanes (4t..4t+3) own queries 4t..4t+3; lane h holds dims
// h*16..h*16+15 of all 4 queries. LDS rows stored as 4 slices at stride 20 words
// (conflict-free broadcast b128). QK/PV use 2-wide packed fp32 FMA (v_pk_fma_f32).
// Static max: scores for query i bounded by ||q_i||/8 = 0.125/rn — no online rescaling.
// omode: 0 = store O/sum + lse, contrib indexed [(b*R+r)*L + pos] (tierA)
//        1 = same but contrib indexed [b*L + pos] (tierB per-round slice)
//        2 = lse only (tierC pass 1)
//        3 = atomic w-weighted add into out (tierC pass 2; needs gm/gs)
__global__ __launch_bounds__(128) void k_flash(const float* __restrict__ q, const float* __restrict__ val,
                                               const int* __restrict__ idx, const int* __restrict__ sb,
                                               const float* __restrict__ rn, float* __restrict__ lse,
                                               const float* __restrict__ gm, const float* __restrict__ gs,
                                               float* __restrict__ out, float* __restrict__ contrib,
                                               int r_fixed, int omode) {
    __shared__ float kt[2][16 * 80];   // per-wave: 16 rows x 4 slices @ stride 20 words
    __shared__ float vt[2][16 * 80];
    __shared__ int   kqs[2][16];
    __shared__ int   kbs[2][16];
    __shared__ float krs[2][16];
    int w   = threadIdx.x >> 6;
    int tid = threadIdx.x & 63;
    int c = blockIdx.x * 2 + w, b = blockIdx.z;
    int r = (r_fixed < 0) ? (int)blockIdx.y : r_fixed;
    size_t sbase = (size_t)(b * R_ + r) * L_;
    int h = tid & 3;
    int posq = c * 64 + (tid >> 2) * 4;           // first query of this lane's quad
    int mls[4];
    #pragma unroll
    for (int qq = 0; qq < 4; ++qq) mls[qq] = idx[sbase + posq + qq];
    int ownpos  = posq + h;
    int myl_own = idx[sbase + ownpos];
    int mybk_own = sb[sbase + ownpos];
    float m_own = 0.125f / rn[(size_t)b * L_ + myl_own];   // = ||q_own||/8
    const float* qb = q   + (size_t)b * L_ * D_;
    const float* vb = val + (size_t)b * L_ * D_;
    v2f qv2[4][8];
    #pragma unroll
    for (int qq = 0; qq < 4; ++qq) {
        const float* qp = qb + (size_t)mls[qq] * D_ + h * 16;
        #pragma unroll
        for (int i = 0; i < 16; i += 4) {
            float4 f = *(const float4*)(qp + i);
            qv2[qq][i >> 1]       = (v2f){f.x, f.y};
            qv2[qq][(i >> 1) + 1] = (v2f){f.z, f.w};
        }
    }
    float ps[4] = {0.0f, 0.0f, 0.0f, 0.0f};
    v2f acc2[4][8];
    #pragma unroll
    for (int qq = 0; qq < 4; ++qq)
        #pragma unroll
        for (int i = 0; i < 8; ++i) acc2[qq][i] = (v2f){0.0f, 0.0f};

    #pragma unroll 1
    for (int s = 0; s < 8; ++s) {   // 8 stages of 16 keys: prev chunk (4) then current (4)
        int ck = ((c + NB_ - 1 + (s >> 2)) & (NB_ - 1)) * 64 + (s & 3) * 16;
        {
            int rw = tid >> 2, cc = tid & 3;
            int kl = idx[sbase + ck + rw];
            const float* kp = qb + (size_t)kl * D_ + cc * 16;
            float* kd = &kt[w][rw * 80 + cc * 20];
            #pragma unroll
            for (int i = 0; i < 16; i += 4) *(float4*)(kd + i) = *(const float4*)(kp + i);
            if (omode != 2) {
                const float* vp = vb + (size_t)kl * D_ + cc * 16;
                float* vd = &vt[w][rw * 80 + cc * 20];
                #pragma unroll
                for (int i = 0; i < 16; i += 4) *(float4*)(vd + i) = *(const float4*)(vp + i);
            }
            if (tid < 16) {
                int kl2 = idx[sbase + ck + tid];
                kqs[w][tid] = kl2;
                kbs[w][tid] = sb[sbase + ck + tid];
                krs[w][tid] = rn[(size_t)b * L_ + kl2] * 0.125f;
            }
        }
        // no barrier: single-wave producer/consumer, lgkmcnt ordering suffices
        #pragma unroll
        for (int j = 0; j < 16; ++j) {
            const float* kpj = &kt[w][j * 80 + h * 20];
            v2f a0 = (v2f){0.f, 0.f}, a1 = a0, a2 = a0, a3 = a0;
            #pragma unroll
            for (int i = 0; i < 16; i += 4) {
                float4 kk = *(const float4*)(kpj + i);
                v2f kA = (v2f){kk.x, kk.y}, kB = (v2f){kk.z, kk.w};
                int i2 = i >> 1;
                a0 = __builtin_elementwise_fma(qv2[0][i2], kA, a0);
                a0 = __builtin_elementwise_fma(qv2[0][i2 + 1], kB, a0);
                a1 = __builtin_elementwise_fma(qv2[1][i2], kA, a1);
                a1 = __builtin_elementwise_fma(qv2[1][i2 + 1], kB, a1);
                a2 = __builtin_elementwise_fma(qv2[2][i2], kA, a2);
                a2 = __builtin_elementwise_fma(qv2[2][i2 + 1], kB, a2);
                a3 = __builtin_elementwise_fma(qv2[3][i2], kA, a3);
                a3 = __builtin_elementwise_fma(qv2[3][i2 + 1], kB, a3);
            }
            float p0 = a0.x + a0.y, p1 = a1.x + a1.y, p2 = a2.x + a2.y, p3 = a3.x + a3.y;
            // 4x4 transpose-reduce across the quad: lane h ends with query h's full dot
            bool b0 = (h & 1), b1 = (h & 2) != 0;
            float u0 = b0 ? p1 : p0;
            float t0 = b0 ? p0 : p1;
            u0 += dpp_xor1(t0);
            float u2 = b0 ? p3 : p2;
            float t2 = b0 ? p2 : p3;
            u2 += dpp_xor1(t2);
            float dot = b1 ? u2 : u0;
            float t3 = b1 ? u0 : u2;
            dot += dpp_xor2(t3);
            float sc = dot * krs[w][j];
            sc = (kbs[w][j] == mybk_own) ? sc : -1.0e9f;   // cross-bucket mask
            if (kqs[w][j] == myl_own) sc = -1.0e5f;         // self mask (overrides, as in ref)
            float p = __expf(sc - m_own);                   // static max: no rescaling ever
            ps[j & 3] += p;
            if (omode != 2) {
                v2f P0 = (v2f){quad_bcast0(p), quad_bcast0(p)};
                v2f P1 = (v2f){quad_bcast1(p), quad_bcast1(p)};
                v2f P2 = (v2f){quad_bcast2(p), quad_bcast2(p)};
                v2f P3 = (v2f){quad_bcast3(p), quad_bcast3(p)};
                const float* vpj = &vt[w][j * 80 + h * 20];
                #pragma unroll
                for (int i = 0; i < 16; i += 4) {
                    float4 vv = *(const float4*)(vpj + i);
                    v2f vA = (v2f){vv.x, vv.y}, vB = (v2f){vv.z, vv.w};
                    int i2 = i >> 1;
                    acc2[0][i2]     = __builtin_elementwise_fma(P0, vA, acc2[0][i2]);
                    acc2[0][i2 + 1] = __builtin_elementwise_fma(P0, vB, acc2[0][i2 + 1]);
                    acc2[1][i2]     = __builtin_elementwise_fma(P1, vA, acc2[1][i2]);
                    acc2[1][i2 + 1] = __builtin_elementwise_fma(P1, vB, acc2[1][i2 + 1]);
                    acc2[2][i2]     = __builtin_elementwise_fma(P2, vA, acc2[2][i2]);
                    acc2[2][i2 + 1] = __builtin_elementwise_fma(P2, vB, acc2[2][i2 + 1]);
                    acc2[3][i2]     = __builtin_elementwise_fma(P3, vA, acc2[3][i2]);
                    acc2[3][i2 + 1] = __builtin_elementwise_fma(P3, vB, acc2[3][i2 + 1]);
                }
            }
        }
    }
    float sum = (ps[0] + ps[1]) + (ps[2] + ps[3]);
    float lse_own, inv_own;
    if (sum > 0.0f) { lse_own = m_own + logf(sum); inv_own = 1.0f / sum; }
    else            { lse_own = -3.0e38f;          inv_own = 0.0f; }   // fully-masked row
    if (omode != 3) lse[sbase + ownpos] = lse_own;
    if (omode == 0 || omode == 1) {
        float ivs[4];
        ivs[0] = quad_bcast0(inv_own); ivs[1] = quad_bcast1(inv_own);
        ivs[2] = quad_bcast2(inv_own); ivs[3] = quad_bcast3(inv_own);
        float* cbase = contrib + ((omode == 0) ? (size_t)(b * R_ + r) * L_ : (size_t)b * L_) * D_;
        #pragma unroll
        for (int qq = 0; qq < 4; ++qq) {
            float* cp = cbase + (size_t)(posq + qq) * D_ + h * 16;
            #pragma unroll
            for (int i = 0; i < 16; i += 4) {
                int i2 = i >> 1;
                float4 o;
                o.x = acc2[qq][i2].x * ivs[qq];     o.y = acc2[qq][i2].y * ivs[qq];
                o.z = acc2[qq][i2 + 1].x * ivs[qq]; o.w = acc2[qq][i2 + 1].y * ivs[qq];
                *(float4*)(cp + i) = o;
            }
        }
    } else if (omode == 3) {
        int brr = b * R_ + r;
        float gmv = gm[brr], gsv = gs[brr];
        float ls4[4], iv4[4];
        ls4[0] = quad_bcast0(lse_own); ls4[1] = quad_bcast1(lse_own);
        ls4[2] = quad_bcast2(lse_own); ls4[3] = quad_bcast3(lse_own);
        iv4[0] = quad_bcast0(inv_own); iv4[1] = quad_bcast1(inv_own);
        iv4[2] = quad_bcast2(inv_own); iv4[3] = quad_bcast3(inv_own);
        #pragma unroll
        for (int qq = 0; qq < 4; ++qq) {
            float wq = __expf(ls4[qq] - gmv) * gsv * iv4[qq];
            float* op = out + ((size_t)b * L_ + mls[qq]) * D_ + h * 16;
            #pragma unroll
            for (int i = 0; i < 8; ++i) {
                unsafeAtomicAdd(op + 2 * i,     wq * acc2[qq][i].x);
                unsafeAtomicAdd(op + 2 * i + 1, wq * acc2[qq][i].y);
            }
        }
    }
}

// ---------------- K5: softmax-over-L normalizers (max + fp64 sum) per (b,r)
__global__ __launch_bounds__(256) void k_wred(const float* __restrict__ lse, float* __restrict__ gm,
                                              float* __restrict__ gs, int r_w) {
    __shared__ float  sm[4];
    __shared__ double sd[4];
    int br = (r_w < 0) ? (int)blockIdx.x : ((int)blockIdx.x * R_ + r_w);
    const float* x = lse + (size_t)br * L_;
    int t = threadIdx.x;
    float mx = -3.0e38f;
    for (int i = t; i < L_; i += 256) mx = fmaxf(mx, x[i]);
    #pragma unroll
    for (int o = 32; o; o >>= 1) mx = fmaxf(mx, __shfl_down(mx, o));
    if ((t & 63) == 0) sm[t >> 6] = mx;
    __syncthreads();
    mx = fmaxf(fmaxf(sm[0], sm[1]), fmaxf(sm[2], sm[3]));
    double s = 0.0;
    for (int i = t; i < L_; i += 256) s += exp((double)x[i] - (double)mx);
    #pragma unroll
    for (int o = 32; o; o >>= 1) s += __shfl_down(s, o);
    if ((t & 63) == 0) sd[t >> 6] = s;
    __syncthreads();
    if (t == 0) { gm[br] = mx; gs[br] = (float)(1.0 / (sd[0] + sd[1] + sd[2] + sd[3])); }
}

// ---------------- K6a: gather all 4 rounds from full contrib, apply w, write out
__global__ __launch_bounds__(256) void k_comb_full(const float* __restrict__ contrib,
                                                   const int* __restrict__ iv,
                                                   const float* __restrict__ lse,
                                                   const float* __restrict__ gm,
                                                   const float* __restrict__ gs,
                                                   float* __restrict__ out) {
    int gid = blockIdx.x * 256 + threadIdx.x;
    int row = gid >> 2;              // b*L + l
    int ch  = (gid & 3) * 16;
    int b = row >> 13, l = row & (L_ - 1);
    float s[16];
    #pragma unroll
    for (int i = 0; i < 16; ++i) s[i] = 0.0f;
    #pragma unroll
    for (int r = 0; r < R_; ++r) {
        int brr = b * R_ + r;
        int pos = iv[(size_t)brr * L_ + l];
        float w = expf(lse[(size_t)brr * L_ + pos] - gm[brr]) * gs[brr];
        const float* cp = contrib + ((size_t)brr * L_ + pos) * D_ + ch;
        #pragma unroll
        for (int i = 0; i < 16; i += 4) {
            float4 f = *(const float4*)(cp + i);
            s[i]   = fmaf(w, f.x, s[i]);   s[i+1] = fmaf(w, f.y, s[i+1]);
            s[i+2] = fmaf(w, f.z, s[i+2]); s[i+3] = fmaf(w, f.w, s[i+3]);
        }
    }
    float* op = out + (size_t)row * D_ + ch;
    #pragma unroll
    for (int i = 0; i < 16; i += 4) {
        float4 o; o.x = s[i]; o.y = s[i+1]; o.z = s[i+2]; o.w = s[i+3];
        *(float4*)(op + i) = o;
    }
}

// ---------------- K6b: gather one round's slice, apply w, accumulate into out
__global__ __launch_bounds__(256) void k_comb_add(const float* __restrict__ contrib,
                                                  const int* __restrict__ iv,
                                                  const float* __restrict__ lse,
                                                  const float* __restrict__ gm,
                                                  const float* __restrict__ gs,
                                                  float* __restrict__ out, int r) {
    int gid = blockIdx.x * 256 + threadIdx.x;
    int row = gid >> 2;              // b*L + l
    int ch  = (gid & 3) * 16;
    int b = row >> 13, l = row & (L_ - 1);
    int brr = b * R_ + r;
    int pos = iv[(size_t)brr * L_ + l];
    float w = expf(lse[(size_t)brr * L_ + pos] - gm[brr]) * gs[brr];
    const float* cp = contrib + ((size_t)b * L_ + pos) * D_ + ch;
    float* op = out + (size_t)row * D_ + ch;
    #pragma unroll
    for (int i = 0; i < 16; i += 4) {
        float4 f = *(const float4*)(cp + i);
        float4 o = *(const float4*)(op + i);
        o.x = fmaf(w, f.x, o.x); o.y = fmaf(w, f.y, o.y);
        o.z = fmaf(w, f.z, o.z); o.w = fmaf(w, f.w, o.w);
        *(float4*)(op + i) = o;
    }
}

// ---------------- workspace layout (bytes)
#define OFF_RMN     0u
#define OFF_RN      2097152u
#define OFF_H       2621440u
#define OFF_IDX     4718592u
#define OFF_SB      6815744u
#define OFF_LSE     8912896u
#define OFF_GM      11010048u
#define OFF_GS      11010304u
#define OFF_INV     11010560u
#define OFF_CONTRIB 13107712u
#define CONTRIB_FULL_BYTES  134217728ull   // B*R*L*D*4 = 128 MiB
#define CONTRIB_SLICE_BYTES 33554432ull    // B*L*D*4   =  32 MiB

extern "C" void kernel_launch(void* const* d_in, const int* in_sizes, int n_in,
                              void* d_out, int out_size, void* d_ws, size_t ws_size,
                              hipStream_t stream) {
    const float* q  = (const float*)d_in[0];
    const float* v  = (const float*)d_in[1];
    const float* rm = (const float*)d_in[2];
    float* out = (float*)d_out;
    char* ws = (char*)d_ws;
    double* rmn = (double*)(ws + OFF_RMN);
    float*  rn  = (float*)(ws + OFF_RN);
    int*    h   = (int*)(ws + OFF_H);
    int*    idx = (int*)(ws + OFF_IDX);
    int*    sb  = (int*)(ws + OFF_SB);
    float*  lse = (float*)(ws + OFF_LSE);
    float*  gm  = (float*)(ws + OFF_GM);
    float*  gs  = (float*)(ws + OFF_GS);
    int*    iv  = (int*)(ws + OFF_INV);
    float*  contrib = (float*)(ws + OFF_CONTRIB);

    int tierA = (ws_size >= (size_t)OFF_CONTRIB + CONTRIB_FULL_BYTES) ? 1 : 0;
    int tierB = (!tierA && ws_size >= (size_t)OFF_CONTRIB + CONTRIB_SLICE_BYTES) ? 1 : 0;

    hipLaunchKernelGGL(k_rmnorm, dim3(B_ * R_), dim3(64), 0, stream, rm, rmn);
    hipLaunchKernelGGL(k_hash, dim3(L_ / 256, R_, B_), dim3(256), 0, stream, q, rmn, rn, h);
    hipLaunchKernelGGL(k_sort, dim3(B_ * R_), dim3(64), 0, stream, h, idx, sb, iv);

    if (tierA) {
        hipLaunchKernelGGL(k_flash, dim3(NB_ / 2, R_, B_), dim3(128), 0, stream, q, v, idx, sb, rn,
                           lse, gm, gs, out, contrib, -1, 0);
        hipLaunchKernelGGL(k_wred, dim3(B_ * R_), dim3(256), 0, stream, lse, gm, gs, -1);
        hipLaunchKernelGGL(k_comb_full, dim3(B_ * L_ * 4 / 256), dim3(256), 0, stream,
                           contrib, iv, lse, gm, gs, out);
    } else if (tierB) {
        hipMemsetAsync(d_out, 0, (size_t)B_ * L_ * D_ * sizeof(float), stream);
        for (int r = 0; r < R_; ++r) {
            hipLaunchKernelGGL(k_flash, dim3(NB_ / 2, 1, B_), dim3(128), 0, stream, q, v, idx, sb, rn,
                               lse, gm, gs, out, contrib, r, 1);
            hipLaunchKernelGGL(k_wred, dim3(B_), dim3(256), 0, stream, lse, gm, gs, r);
            hipLaunchKernelGGL(k_comb_add, dim3(B_ * L_ * 4 / 256), dim3(256), 0, stream,
                               contrib, iv, lse, gm, gs, out, r);
        }
    } else {
        // tier C: two flash passes (lse-only, then atomic w-weighted accumulate)
        hipMemsetAsync(d_out, 0, (size_t)B_ * L_ * D_ * sizeof(float), stream);
        hipLaunchKernelGGL(k_flash, dim3(NB_ / 2, R_, B_), dim3(128), 0, stream, q, v, idx, sb, rn,
                           lse, gm, gs, out, contrib, -1, 2);
        hipLaunchKernelGGL(k_wred, dim3(B_ * R_), dim3(256), 0, stream, lse, gm, gs, -1);
        hipLaunchKernelGGL(k_flash, dim3(NB_ / 2, R_, B_), dim3(128), 0, stream, q, v, idx, sb, rn,
                           lse, gm, gs, out, contrib, -1, 3);
    }
}